// Round 1
// baseline (237.013 us; speedup 1.0000x reference)
//
#include <hip/hip_runtime.h>
#include <hip/hip_bf16.h>

// Problem constants
#define BATCH  128
#define HWN    196          // (224/16)^2 patches per sample
#define HIDN   768          // output channels
#define KN     768          // 3*16*16 reduction dim
#define IMGSZ  224
#define IMG2   (224*224)    // 50176

// Tiling
#define BM 128
#define BN 128
#define BK 32
#define LDK 40              // padded LDS K-stride (elems); 80 B rows

typedef __attribute__((ext_vector_type(8))) short bf16x8;
typedef __attribute__((ext_vector_type(4))) float floatx4;

static __device__ __forceinline__ short f2bf(float f) {
    __hip_bfloat16 h = __float2bfloat16(f);   // RNE
    return __builtin_bit_cast(short, h);
}

// out[r, n] = sum_k x[b, patch perm[r], k] * W[n, k] + bias[n]
// r = b*196 + j ; p = perm[r]; k = c*256 + iy*16 + ix
__global__ __launch_bounds__(256, 3)
void patch_gemm(const float* __restrict__ x, const float* __restrict__ W,
                const float* __restrict__ bias, const int* __restrict__ perm,
                float* __restrict__ out)
{
    __shared__ __align__(16) short As[BM * LDK];
    __shared__ __align__(16) short Bs[BN * LDK];

    const int tid = threadIdx.x;
    const int bm  = blockIdx.x;   // 0..195  (M tiles)
    const int bn  = blockIdx.y;   // 0..5    (N tiles)

    // ---- staging assignment: thread t stages 16 contiguous k-values of one row
    const int srow  = tid >> 1;   // 0..127
    const int shalf = tid & 1;    // which 16-wide half of the 32-k tile

    // A-row source: output row -> permuted patch of sample b
    const int gr = bm * BM + srow;        // global output row, < 25088
    const int b  = gr / HWN;
    const int p  = perm[gr];              // patch index within sample
    const int py = p / 14, px = p % 14;
    const float* arow = x + (size_t)b * 3 * IMG2 + (py * 16) * IMGSZ + px * 16;

    // B-row source: W[n][k], row-major K
    const float* brow = W + (size_t)(bn * BN + srow) * KN;

    // ---- wave/fragment coords
    const int lane = tid & 63;
    const int wave = tid >> 6;
    const int wm = (wave >> 1) * 64;      // wave row offset in tile
    const int wn = (wave & 1) * 64;       // wave col offset in tile
    const int lr = lane & 15;             // fragment row/col
    const int lq = lane >> 4;             // quad (k-group / acc-row group)

    floatx4 acc[4][4] = {};

    for (int k0 = 0; k0 < KN; k0 += BK) {
        // ---- stage A tile (gathered patch pixels, fp32 -> bf16)
        {
            const int k   = k0 + shalf * 16;
            const int c   = k >> 8;
            const int iy  = (k & 255) >> 4;
            const float* src = arow + c * IMG2 + iy * IMGSZ;   // 16 contiguous floats
            float4 f0 = *(const float4*)(src + 0);
            float4 f1 = *(const float4*)(src + 4);
            float4 f2 = *(const float4*)(src + 8);
            float4 f3 = *(const float4*)(src + 12);
            bf16x8 v0, v1;
            v0[0]=f2bf(f0.x); v0[1]=f2bf(f0.y); v0[2]=f2bf(f0.z); v0[3]=f2bf(f0.w);
            v0[4]=f2bf(f1.x); v0[5]=f2bf(f1.y); v0[6]=f2bf(f1.z); v0[7]=f2bf(f1.w);
            v1[0]=f2bf(f2.x); v1[1]=f2bf(f2.y); v1[2]=f2bf(f2.z); v1[3]=f2bf(f2.w);
            v1[4]=f2bf(f3.x); v1[5]=f2bf(f3.y); v1[6]=f2bf(f3.z); v1[7]=f2bf(f3.w);
            *(bf16x8*)&As[srow * LDK + shalf * 16]     = v0;
            *(bf16x8*)&As[srow * LDK + shalf * 16 + 8] = v1;
        }
        // ---- stage B tile (weights, fp32 -> bf16)
        {
            const float* src = brow + k0 + shalf * 16;
            float4 f0 = *(const float4*)(src + 0);
            float4 f1 = *(const float4*)(src + 4);
            float4 f2 = *(const float4*)(src + 8);
            float4 f3 = *(const float4*)(src + 12);
            bf16x8 v0, v1;
            v0[0]=f2bf(f0.x); v0[1]=f2bf(f0.y); v0[2]=f2bf(f0.z); v0[3]=f2bf(f0.w);
            v0[4]=f2bf(f1.x); v0[5]=f2bf(f1.y); v0[6]=f2bf(f1.z); v0[7]=f2bf(f1.w);
            v1[0]=f2bf(f2.x); v1[1]=f2bf(f2.y); v1[2]=f2bf(f2.z); v1[3]=f2bf(f2.w);
            v1[4]=f2bf(f3.x); v1[5]=f2bf(f3.y); v1[6]=f2bf(f3.z); v1[7]=f2bf(f3.w);
            *(bf16x8*)&Bs[srow * LDK + shalf * 16]     = v0;
            *(bf16x8*)&Bs[srow * LDK + shalf * 16 + 8] = v1;
        }
        __syncthreads();

        // ---- fragments + MFMA
        bf16x8 bfrag[4];
        #pragma unroll
        for (int j = 0; j < 4; ++j)
            bfrag[j] = *(const bf16x8*)&Bs[(wn + j * 16 + lr) * LDK + lq * 8];
        #pragma unroll
        for (int i = 0; i < 4; ++i) {
            bf16x8 afrag = *(const bf16x8*)&As[(wm + i * 16 + lr) * LDK + lq * 8];
            #pragma unroll
            for (int j = 0; j < 4; ++j)
                acc[i][j] = __builtin_amdgcn_mfma_f32_16x16x32_bf16(
                                afrag, bfrag[j], acc[i][j], 0, 0, 0);
        }
        __syncthreads();
    }

    // ---- epilogue: bias + store (C/D layout: col = lane&15, row = quad*4 + reg)
    #pragma unroll
    for (int j = 0; j < 4; ++j) {
        const int gc = bn * BN + wn + j * 16 + lr;
        const float bv = bias[gc];
        #pragma unroll
        for (int i = 0; i < 4; ++i) {
            const int grow = bm * BM + wm + i * 16 + lq * 4;
            float* op = out + (size_t)grow * HIDN + gc;
            #pragma unroll
            for (int r = 0; r < 4; ++r)
                op[(size_t)r * HIDN] = acc[i][j][r] + bv;
        }
    }
}

extern "C" void kernel_launch(void* const* d_in, const int* in_sizes, int n_in,
                              void* d_out, int out_size, void* d_ws, size_t ws_size,
                              hipStream_t stream) {
    const float* x    = (const float*)d_in[0];
    const float* W    = (const float*)d_in[1];
    const float* bias = (const float*)d_in[2];
    const int*   perm = (const int*)d_in[3];
    float* out = (float*)d_out;

    dim3 grid(196, 6);   // M tiles x N tiles (25088/128, 768/128)
    patch_gemm<<<grid, dim3(256), 0, stream>>>(x, W, bias, perm, out);
}

// Round 2
// 192.314 us; speedup vs baseline: 1.2324x; 1.2324x over previous
//
#include <hip/hip_runtime.h>
#include <hip/hip_bf16.h>

// Problem constants
#define BATCH  128
#define HWN    196          // (224/16)^2 patches per sample
#define HIDN   768
#define KN     768          // 3*16*16
#define IMGSZ  224
#define IMG2   (224*224)
#define MTOT   (BATCH*HWN)  // 25088 output rows

// GEMM tiling (m97 structure)
#define BM 128
#define BN 128
#define BK 32

typedef __attribute__((ext_vector_type(8))) short bf16x8;
typedef __attribute__((ext_vector_type(4))) float floatx4;

#define GP(p) ((const __attribute__((address_space(1))) void*)(p))
#define SP(p) ((__attribute__((address_space(3))) void*)(p))

static __device__ __forceinline__ short f2bf(float f) {
    __hip_bfloat16 h = __float2bfloat16(f);   // RNE
    return __builtin_bit_cast(short, h);
}

static __device__ __forceinline__ bf16x8 cvt8(const float* __restrict__ src) {
    float4 f0 = *(const float4*)(src);
    float4 f1 = *(const float4*)(src + 4);
    bf16x8 v;
    v[0]=f2bf(f0.x); v[1]=f2bf(f0.y); v[2]=f2bf(f0.z); v[3]=f2bf(f0.w);
    v[4]=f2bf(f1.x); v[5]=f2bf(f1.y); v[6]=f2bf(f1.z); v[7]=f2bf(f1.w);
    return v;
}

// ---------------------------------------------------------------------------
// prep_A: gather + convert. A[gr, k] = bf16(x[b, c, perm-patch pixel]) with
// gr = b*196 + j, p = perm[gr], k = c*256 + iy*16 + ix.
// One thread handles 16 consecutive k (one (c,iy) segment = 16 aligned floats).
// Writes are thread-contiguous 32 B -> perfectly coalesced.
// Total threads = 25088 * 48 = 1,204,224 -> 4704 blocks of 256.
// ---------------------------------------------------------------------------
__global__ __launch_bounds__(256)
void prep_A(const float* __restrict__ x, const int* __restrict__ perm,
            unsigned short* __restrict__ A)
{
    const int idx = blockIdx.x * 256 + threadIdx.x;   // < 25088*48
    const int gr  = idx / 48;
    const int seg = idx - gr * 48;                    // 0..47
    const int b   = gr / HWN;
    const int p   = perm[gr];
    const int py  = p / 14, px = p - py * 14;
    const int c   = seg >> 4;                         // 0..2
    const int iy  = seg & 15;                         // 0..15

    const float* src = x + (size_t)b * 3 * IMG2 + (size_t)c * IMG2
                         + (size_t)(py * 16 + iy) * IMGSZ + px * 16;
    bf16x8 v0 = cvt8(src);
    bf16x8 v1 = cvt8(src + 8);
    unsigned short* dst = A + (size_t)gr * KN + seg * 16;
    *(bf16x8*)(dst)     = v0;
    *(bf16x8*)(dst + 8) = v1;
}

// ---------------------------------------------------------------------------
// prep_W: fp32 -> bf16, 768*768 elems, 8 per thread. 288 blocks of 256.
// ---------------------------------------------------------------------------
__global__ __launch_bounds__(256)
void prep_W(const float* __restrict__ W, unsigned short* __restrict__ Wb)
{
    const int idx = blockIdx.x * 256 + threadIdx.x;   // < 73728
    const float* src = W + (size_t)idx * 8;
    *(bf16x8*)(Wb + (size_t)idx * 8) = cvt8(src);
}

// ---------------------------------------------------------------------------
// gemm: C[r,n] = sum_k A[r,k]*Wb[n,k] + bias[n]
// m97 structure: 128x128 tile, BK=32, unpadded 64 B LDS rows,
// global_load_lds width=16 async staging (2 A + 2 B per thread per iter).
// ---------------------------------------------------------------------------
__global__ __launch_bounds__(256, 3)
void gemm(const unsigned short* __restrict__ A, const unsigned short* __restrict__ Wb,
          const float* __restrict__ bias, float* __restrict__ out)
{
    __shared__ __align__(16) unsigned short As[BM * BK];  // 8 KB
    __shared__ __align__(16) unsigned short Bs[BN * BK];  // 8 KB

    const int tid = threadIdx.x;
    const int bm  = blockIdx.x;   // 0..195
    const int bn  = blockIdx.y;   // 0..5

    // staging map: thread t loads 16 B = 8 bf16 of row (t>>2), k-seg (t&3).
    // LDS offset = tid*8 elems = waveBase + lane*16 B (wave-uniform + lane*size).
    const int srow = tid >> 2;
    const int sseg = tid & 3;
    const unsigned short* ga = A  + (size_t)(bm * BM + srow) * KN + sseg * 8;
    const unsigned short* gb = Wb + (size_t)(bn * BN + srow) * KN + sseg * 8;

    // wave/fragment coords
    const int lane = tid & 63;
    const int wave = tid >> 6;
    const int wm = (wave >> 1) * 64;
    const int wn = (wave & 1) * 64;
    const int lr = lane & 15;
    const int lq = lane >> 4;

    floatx4 acc[4][4] = {};

    for (int k0 = 0; k0 < KN; k0 += BK) {
        __builtin_amdgcn_global_load_lds(GP(ga + k0),            SP(&As[tid * 8]),        16, 0, 0);
        __builtin_amdgcn_global_load_lds(GP(ga + 64 * KN + k0),  SP(&As[2048 + tid * 8]), 16, 0, 0);
        __builtin_amdgcn_global_load_lds(GP(gb + k0),            SP(&Bs[tid * 8]),        16, 0, 0);
        __builtin_amdgcn_global_load_lds(GP(gb + 64 * KN + k0),  SP(&Bs[2048 + tid * 8]), 16, 0, 0);
        __syncthreads();

        bf16x8 bfrag[4];
        #pragma unroll
        for (int j = 0; j < 4; ++j)
            bfrag[j] = *(const bf16x8*)&Bs[(wn + j * 16 + lr) * BK + lq * 8];
        #pragma unroll
        for (int i = 0; i < 4; ++i) {
            bf16x8 afrag = *(const bf16x8*)&As[(wm + i * 16 + lr) * BK + lq * 8];
            #pragma unroll
            for (int j = 0; j < 4; ++j)
                acc[i][j] = __builtin_amdgcn_mfma_f32_16x16x32_bf16(
                                afrag, bfrag[j], acc[i][j], 0, 0, 0);
        }
        __syncthreads();
    }

    // epilogue: bias + store (C/D: col = lane&15, row = quad*4 + reg)
    #pragma unroll
    for (int j = 0; j < 4; ++j) {
        const int gc = bn * BN + wn + j * 16 + lr;
        const float bv = bias[gc];
        #pragma unroll
        for (int i = 0; i < 4; ++i) {
            const int grow = bm * BM + wm + i * 16 + lq * 4;
            float* op = out + (size_t)grow * HIDN + gc;
            #pragma unroll
            for (int r = 0; r < 4; ++r)
                op[(size_t)r * HIDN] = acc[i][j][r] + bv;
        }
    }
}

extern "C" void kernel_launch(void* const* d_in, const int* in_sizes, int n_in,
                              void* d_out, int out_size, void* d_ws, size_t ws_size,
                              hipStream_t stream) {
    const float* x    = (const float*)d_in[0];
    const float* W    = (const float*)d_in[1];
    const float* bias = (const float*)d_in[2];
    const int*   perm = (const int*)d_in[3];
    float* out = (float*)d_out;

    // workspace layout: A bf16 [25088*768] (38.5 MB), Wb bf16 [768*768] (1.2 MB)
    unsigned short* A  = (unsigned short*)d_ws;
    unsigned short* Wb = A + (size_t)MTOT * KN;

    prep_A<<<dim3(MTOT * 48 / 256), dim3(256), 0, stream>>>(x, perm, A);
    prep_W<<<dim3(KN * HIDN / 8 / 256), dim3(256), 0, stream>>>(W, Wb);
    gemm<<<dim3(MTOT / BM, HIDN / BN), dim3(256), 0, stream>>>(A, Wb, bias, out);
}